// Round 5
// baseline (87.481 us; speedup 1.0000x reference)
//
#include <hip/hip_runtime.h>
#include <math.h>

#define NTOK 4096
#define NDIM 1024
#define KTOT 2048
#define NEXP 64
#define TPB_TOK 64           // tokens per block (4 MFMA A-tiles) -> W amortized 4x
#define KBLK 512             // K per block (4 blocks per token-tile split K)
#define NWAVE 8              // intra-block split-K waves
#define KCH  (KBLK / NWAVE)  // 64 k per wave
#define NSTEP (KCH / 32)     // 2 mfma K-steps per wave
#define RS   68              // LDS row stride (floats) for the reduce buffer
#define NTILE (NTOK / TPB_TOK)   // 64 token tiles; grid = 64*4 = 256 blocks

typedef _Float16 half8 __attribute__((ext_vector_type(8)));
typedef float    floatx4 __attribute__((ext_vector_type(4)));

#define XSCALE 16.0f
#define WSCALE 1024.0f
#define INVSCALE (1.0f / (16.0f * 1024.0f))

struct h2pair { _Float16 h, l; };
__device__ __forceinline__ h2pair split2(float v) {
    h2pair r;
    r.h = (_Float16)v;
    r.l = (_Float16)(v - (float)r.h);
    return r;
}

// ---------------------------------------------------------------------------
// prep_w: W (fp32) -> scaled fp16 hi/lo planes in FRAGMENT-MAJOR layout
//   WhT[((k>>3)*NEXP + e)*8 + (k&7)]  (256 B contiguous per B-fragment load)
// Also computes ||w_e||^2.  grid = 64 blocks x 256 threads.
// ---------------------------------------------------------------------------
__global__ __launch_bounds__(256) void prep_w(const float* __restrict__ W,
                                              _Float16* __restrict__ WhT,
                                              _Float16* __restrict__ WlT,
                                              float* __restrict__ nrm) {
    const int e = blockIdx.x, t = threadIdx.x;   // t = k-octet 0..255
    const float* row = W + (size_t)e * KTOT + t * 8;
    const float4 a = *reinterpret_cast<const float4*>(row);
    const float4 b = *reinterpret_cast<const float4*>(row + 4);
    float ss = fmaf(a.x, a.x, fmaf(a.y, a.y, fmaf(a.z, a.z, fmaf(a.w, a.w, 0.f))));
    ss = fmaf(b.x, b.x, fmaf(b.y, b.y, fmaf(b.z, b.z, fmaf(b.w, b.w, ss))));

    const h2pair p0 = split2(a.x * WSCALE), p1 = split2(a.y * WSCALE);
    const h2pair p2 = split2(a.z * WSCALE), p3 = split2(a.w * WSCALE);
    const h2pair p4 = split2(b.x * WSCALE), p5 = split2(b.y * WSCALE);
    const h2pair p6 = split2(b.z * WSCALE), p7 = split2(b.w * WSCALE);
    half8 h, l;
    h[0]=p0.h; h[1]=p1.h; h[2]=p2.h; h[3]=p3.h; h[4]=p4.h; h[5]=p5.h; h[6]=p6.h; h[7]=p7.h;
    l[0]=p0.l; l[1]=p1.l; l[2]=p2.l; l[3]=p3.l; l[4]=p4.l; l[5]=p5.l; l[6]=p6.l; l[7]=p7.l;
    const size_t idx = ((size_t)t * NEXP + e) * 8;
    *reinterpret_cast<half8*>(WhT + idx) = h;
    *reinterpret_cast<half8*>(WlT + idx) = l;

    #pragma unroll
    for (int off = 32; off > 0; off >>= 1) ss += __shfl_down(ss, off, 64);
    __shared__ float red[4];
    const int lane = t & 63, wv = t >> 6;
    if (lane == 0) red[wv] = ss;
    __syncthreads();
    if (t == 0) nrm[e] = (red[0] + red[1]) + (red[2] + red[3]);
}

// ---------------------------------------------------------------------------
// gate_main: 256 blocks = 64 token-tiles (64 tokens) x 4 K-quarters.
// R4 post-mortem: fixed harness overhead ~64us; kernel budget ~20us; R3's
// direct counters show the main loop vmem-issue/latency bound (<12% all
// pipes, ~1.7 TB/s effective).  This version deepens W amortization: each
// B-fragment load feeds FOUR 16-token A-tiles -> per-block vmem traffic
// 384KB -> 256KB and MFMA:vmem ratio doubles vs R4.
// Each wave handles k-chunk [kq*512 + wv*64, +64) for 64 tokens.
// ---------------------------------------------------------------------------
__global__ __launch_bounds__(512) void gate_main(const float* __restrict__ t1,
                                                 const float* __restrict__ t2,
                                                 const _Float16* __restrict__ WhT,
                                                 const _Float16* __restrict__ WlT,
                                                 float* __restrict__ dotp,
                                                 float* __restrict__ xnp) {
    __shared__ float Sd[NWAVE][TPB_TOK * RS];  // 8 x 64x64 partial dots (139 KB)
    __shared__ float Cn[NWAVE][TPB_TOK];       // per-wave per-token ||x||^2 partials

    const int tid  = threadIdx.x;
    const int lane = tid & 63;
    const int wv   = tid >> 6;            // 0..7 = intra-block split-K chunk
    const int bid  = blockIdx.x;
    const int tile = bid >> 2;            // token tile 0..63
    const int kq   = bid & 3;             // K quarter 0..3
    const int tok0 = tile * TPB_TOK;
    const int kbase = kq * KBLK + wv * KCH;
    const int n  = lane & 15;             // fragment row (token / expert)
    const int fq = lane >> 4;             // k-octet selector

    // X: four A-tiles; KCH=64 divides NDIM so each chunk is in one tensor
    const float* __restrict__ xsrc = (kbase < NDIM) ? t1 : t2;
    const int koff = (kbase < NDIM) ? kbase : (kbase - NDIM);
    const float* __restrict__ xb = xsrc + (size_t)(tok0 + n) * NDIM + koff + fq * 8;
    // W: fragment-major; k-octet index = kbase/8 + s*4 + fq, expert row 16j+n
    const _Float16* __restrict__ whb = WhT + ((size_t)(kbase >> 3) + fq) * (NEXP * 8) + n * 8;
    const _Float16* __restrict__ wlb = WlT + ((size_t)(kbase >> 3) + fq) * (NEXP * 8) + n * 8;

    floatx4 acc[4][4];                    // [A-tile][expert-quadrant]
    #pragma unroll
    for (int tt = 0; tt < 4; ++tt)
        #pragma unroll
        for (int j = 0; j < 4; ++j) { acc[tt][j][0]=0.f; acc[tt][j][1]=0.f; acc[tt][j][2]=0.f; acc[tt][j][3]=0.f; }
    float ssx[4] = {0.f, 0.f, 0.f, 0.f};

    #pragma unroll
    for (int s = 0; s < NSTEP; ++s) {
        half8 bh[4], bl[4];
        #pragma unroll
        for (int j = 0; j < 4; ++j) {
            bh[j] = *reinterpret_cast<const half8*>(whb + (size_t)s * 4 * (NEXP * 8) + j * 128);
            bl[j] = *reinterpret_cast<const half8*>(wlb + (size_t)s * 4 * (NEXP * 8) + j * 128);
        }
        half8 ah[4], al[4];
        #pragma unroll
        for (int tt = 0; tt < 4; ++tt) {
            const float* xp = xb + (size_t)tt * 16 * NDIM + s * 32;
            const float4 xa = *reinterpret_cast<const float4*>(xp);
            const float4 xc = *reinterpret_cast<const float4*>(xp + 4);
            ssx[tt] = fmaf(xa.x, xa.x, fmaf(xa.y, xa.y, fmaf(xa.z, xa.z, fmaf(xa.w, xa.w, ssx[tt]))));
            ssx[tt] = fmaf(xc.x, xc.x, fmaf(xc.y, xc.y, fmaf(xc.z, xc.z, fmaf(xc.w, xc.w, ssx[tt]))));
            const h2pair q0 = split2(xa.x * XSCALE), q1 = split2(xa.y * XSCALE);
            const h2pair q2 = split2(xa.z * XSCALE), q3 = split2(xa.w * XSCALE);
            const h2pair q4 = split2(xc.x * XSCALE), q5 = split2(xc.y * XSCALE);
            const h2pair q6 = split2(xc.z * XSCALE), q7 = split2(xc.w * XSCALE);
            ah[tt][0]=q0.h; ah[tt][1]=q1.h; ah[tt][2]=q2.h; ah[tt][3]=q3.h;
            ah[tt][4]=q4.h; ah[tt][5]=q5.h; ah[tt][6]=q6.h; ah[tt][7]=q7.h;
            al[tt][0]=q0.l; al[tt][1]=q1.l; al[tt][2]=q2.l; al[tt][3]=q3.l;
            al[tt][4]=q4.l; al[tt][5]=q5.l; al[tt][6]=q6.l; al[tt][7]=q7.l;
        }
        // Each B fragment feeds all four A-tiles: W vmem amortized 4x.
        #pragma unroll
        for (int j = 0; j < 4; ++j)
            #pragma unroll
            for (int tt = 0; tt < 4; ++tt)
                acc[tt][j] = __builtin_amdgcn_mfma_f32_16x16x32_f16(ah[tt], bh[j], acc[tt][j], 0, 0, 0);
        #pragma unroll
        for (int j = 0; j < 4; ++j)
            #pragma unroll
            for (int tt = 0; tt < 4; ++tt)
                acc[tt][j] = __builtin_amdgcn_mfma_f32_16x16x32_f16(al[tt], bh[j], acc[tt][j], 0, 0, 0);
        #pragma unroll
        for (int j = 0; j < 4; ++j)
            #pragma unroll
            for (int tt = 0; tt < 4; ++tt)
                acc[tt][j] = __builtin_amdgcn_mfma_f32_16x16x32_f16(ah[tt], bl[j], acc[tt][j], 0, 0, 0);
    }

    // ---- deposit partial dots (C/D layout: token = tt*16 + fq*4+i, expert 16j+n)
    #pragma unroll
    for (int tt = 0; tt < 4; ++tt)
        #pragma unroll
        for (int j = 0; j < 4; ++j)
            #pragma unroll
            for (int i = 0; i < 4; ++i)
                Sd[wv][(tt * 16 + fq * 4 + i) * RS + 16 * j + n] = acc[tt][j][i];

    // ---- token norm partials: combine the 4 fq-lanes of each token ----
    #pragma unroll
    for (int tt = 0; tt < 4; ++tt) {
        float ss = ssx[tt];
        ss += __shfl_xor(ss, 16, 64);
        ss += __shfl_xor(ss, 32, 64);
        if (lane < 16) Cn[wv][tt * 16 + lane] = ss;
    }
    __syncthreads();

    // ---- reduce over the 8 intra-block waves; write partials (wave w: 8 tokens)
    #pragma unroll
    for (int tt = 0; tt < 8; ++tt) {
        const int t = wv * 8 + tt;
        float gsum = 0.f, csum = 0.f;
        #pragma unroll
        for (int w = 0; w < NWAVE; ++w) {
            gsum += Sd[w][t * RS + lane];
            csum += Cn[w][t];
        }
        dotp[((size_t)(tile * 4 + kq) * TPB_TOK + t) * NEXP + lane] = gsum;
        if (lane == 0) xnp[(size_t)(tile * 4 + kq) * TPB_TOK + t] = csum;
    }
}

// ---------------------------------------------------------------------------
// finalize: one wave per token — combine the 4 K-quarter partials, then
// logit = -sqrt(||x||^2 - 2 x.w + ||w||^2), top-2, softmax, scatter.
// grid = 512 blocks x 512 threads (8 waves = 8 tokens per block).
// (top-2/softmax code path byte-identical to all prior passing rounds)
// ---------------------------------------------------------------------------
__global__ __launch_bounds__(512) void finalize(const float* __restrict__ dotp,
                                                const float* __restrict__ xnp,
                                                const float* __restrict__ nrm,
                                                float* __restrict__ out) {
    const int tid  = threadIdx.x;
    const int lane = tid & 63;
    const int wv   = tid >> 6;
    const int tok  = blockIdx.x * 8 + wv;
    const int tile = tok >> 6;            // /TPB_TOK
    const int t    = tok & 63;

    float g = 0.f, c = 0.f;
    #pragma unroll
    for (int kq = 0; kq < 4; ++kq) {
        g += dotp[((size_t)(tile * 4 + kq) * TPB_TOK + t) * NEXP + lane];
        c += xnp[(size_t)(tile * 4 + kq) * TPB_TOK + t];
    }
    const float S = fmaf(-2.f * INVSCALE, g, c) + nrm[lane];
    const float logit = -sqrtf(S);

    float v1 = logit; int i1 = lane;
    #pragma unroll
    for (int off = 32; off > 0; off >>= 1) {
        float ov = __shfl_xor(v1, off, 64);
        int   oi = __shfl_xor(i1, off, 64);
        if (ov > v1 || (ov == v1 && oi < i1)) { v1 = ov; i1 = oi; }
    }
    float v2 = (lane == i1) ? -__builtin_inff() : logit;
    int   i2 = lane;
    #pragma unroll
    for (int off = 32; off > 0; off >>= 1) {
        float ov = __shfl_xor(v2, off, 64);
        int   oi = __shfl_xor(i2, off, 64);
        if (ov > v2 || (ov == v2 && oi < i2)) { v2 = ov; i2 = oi; }
    }
    const float e2  = expf(v2 - v1);
    const float inv = 1.f / (1.f + e2);
    const float o = (lane == i1) ? inv : ((lane == i2) ? e2 * inv : 0.f);
    out[(size_t)tok * NEXP + lane] = o;
}

// ---------------------------------------------------------------------------
extern "C" void kernel_launch(void* const* d_in, const int* in_sizes, int n_in,
                              void* d_out, int out_size, void* d_ws, size_t ws_size,
                              hipStream_t stream) {
    const float* t1 = (const float*)d_in[0];
    const float* t2 = (const float*)d_in[1];
    const float* W  = (const float*)d_in[2];
    float* out = (float*)d_out;

    char* ws = (char*)d_ws;
    float*    nrm  = (float*)ws;                        // 64 floats
    _Float16* WhT  = (_Float16*)(nrm + NEXP);           // 131072 halves (256 KB)
    _Float16* WlT  = WhT + (size_t)NEXP * KTOT;         // 256 KB
    float*    dotp = (float*)(WlT + (size_t)NEXP * KTOT);   // 64*4*64*64 floats (4 MB)
    float*    xnp  = dotp + (size_t)NTILE * 4 * TPB_TOK * NEXP; // 16384 floats

    prep_w<<<NEXP, 256, 0, stream>>>(W, WhT, WlT, nrm);
    gate_main<<<NTILE * 4, 512, 0, stream>>>(t1, t2, WhT, WlT, dotp, xnp);
    finalize<<<NTOK / 8, 512, 0, stream>>>(dotp, xnp, nrm, out);
}

// Round 6
// 85.048 us; speedup vs baseline: 1.0286x; 1.0286x over previous
//
#include <hip/hip_runtime.h>
#include <math.h>

#define NTOK 4096
#define NDIM 1024
#define KTOT 2048
#define NEXP 64
#define TPB_TOK 32           // tokens per block (2 MFMA A-tiles) -> W amortized 2x
#define KBLK 1024            // K per block (2 blocks per token-tile split K)
#define NWAVE 8              // intra-block split-K waves
#define KCH  (KBLK / NWAVE)  // 128 k per wave
#define NSTEP (KCH / 32)     // 4 mfma K-steps per wave
#define RS   68              // LDS row stride (floats) for the reduce buffer
#define NTILE (NTOK / TPB_TOK)   // 128 token tiles

typedef _Float16 half8 __attribute__((ext_vector_type(8)));
typedef float    floatx4 __attribute__((ext_vector_type(4)));

#define XSCALE 16.0f
#define WSCALE 1024.0f
#define INVSCALE (1.0f / (16.0f * 1024.0f))

struct h2pair { _Float16 h, l; };
__device__ __forceinline__ h2pair split2(float v) {
    h2pair r;
    r.h = (_Float16)v;
    r.l = (_Float16)(v - (float)r.h);
    return r;
}

// ---------------------------------------------------------------------------
// REVERT to the R4 configuration — best verified this session (84.7 us).
// Session ledger: occupancy 2x (null), full fusion (+21 us), W-amortize 2x
// (-1.6 us), W-amortize 4x (+2.8 us).  Fixed harness cost ~64 us (268 MB
// poison fill @ ~45 us + restores + gaps, measured via R3's fused kernel:
// 107.4 total - 43.2 kernel).  Controllable window ~20 us with a ~12 us
// floor (32 MB X read @ 6.3 TB/s + prep/finalize + 3 launches).
// ---------------------------------------------------------------------------
__global__ __launch_bounds__(256) void prep_w(const float* __restrict__ W,
                                              _Float16* __restrict__ WhT,
                                              _Float16* __restrict__ WlT,
                                              float* __restrict__ nrm) {
    const int e = blockIdx.x, t = threadIdx.x;   // t = k-octet 0..255
    const float* row = W + (size_t)e * KTOT + t * 8;
    const float4 a = *reinterpret_cast<const float4*>(row);
    const float4 b = *reinterpret_cast<const float4*>(row + 4);
    float ss = fmaf(a.x, a.x, fmaf(a.y, a.y, fmaf(a.z, a.z, fmaf(a.w, a.w, 0.f))));
    ss = fmaf(b.x, b.x, fmaf(b.y, b.y, fmaf(b.z, b.z, fmaf(b.w, b.w, ss))));

    const h2pair p0 = split2(a.x * WSCALE), p1 = split2(a.y * WSCALE);
    const h2pair p2 = split2(a.z * WSCALE), p3 = split2(a.w * WSCALE);
    const h2pair p4 = split2(b.x * WSCALE), p5 = split2(b.y * WSCALE);
    const h2pair p6 = split2(b.z * WSCALE), p7 = split2(b.w * WSCALE);
    half8 h, l;
    h[0]=p0.h; h[1]=p1.h; h[2]=p2.h; h[3]=p3.h; h[4]=p4.h; h[5]=p5.h; h[6]=p6.h; h[7]=p7.h;
    l[0]=p0.l; l[1]=p1.l; l[2]=p2.l; l[3]=p3.l; l[4]=p4.l; l[5]=p5.l; l[6]=p6.l; l[7]=p7.l;
    const size_t idx = ((size_t)t * NEXP + e) * 8;
    *reinterpret_cast<half8*>(WhT + idx) = h;
    *reinterpret_cast<half8*>(WlT + idx) = l;

    #pragma unroll
    for (int off = 32; off > 0; off >>= 1) ss += __shfl_down(ss, off, 64);
    __shared__ float red[4];
    const int lane = t & 63, wv = t >> 6;
    if (lane == 0) red[wv] = ss;
    __syncthreads();
    if (t == 0) nrm[e] = (red[0] + red[1]) + (red[2] + red[3]);
}

// ---------------------------------------------------------------------------
// gate_main: 256 blocks = 128 token-tiles (32 tokens) x 2 K-halves.
// Each B-fragment load feeds TWO 16-token A-tiles (W vmem amortized 2x).
// Each wave handles k-chunk [kb*1024 + wv*128, +128) for 32 tokens.
// Partial dot-sums + ||x||^2 partials go to workspace; finalize combines.
// ---------------------------------------------------------------------------
__global__ __launch_bounds__(512) void gate_main(const float* __restrict__ t1,
                                                 const float* __restrict__ t2,
                                                 const _Float16* __restrict__ WhT,
                                                 const _Float16* __restrict__ WlT,
                                                 float* __restrict__ dotp,
                                                 float* __restrict__ xnp) {
    __shared__ float Sd[NWAVE][TPB_TOK * RS];  // per-wave 32x64 partial dots
    __shared__ float Cn[NWAVE][TPB_TOK];       // per-wave per-token ||x||^2 partials

    const int tid  = threadIdx.x;
    const int lane = tid & 63;
    const int wv   = tid >> 6;            // 0..7 = intra-block split-K chunk
    const int bid  = blockIdx.x;
    const int tile = bid >> 1;            // token tile 0..127
    const int kb   = bid & 1;             // K half 0..1
    const int tok0 = tile * TPB_TOK;
    const int kbase = kb * KBLK + wv * KCH;
    const int n  = lane & 15;             // fragment row (token / expert)
    const int fq = lane >> 4;             // k-octet selector

    // X: two A-tiles; KCH=128 divides NDIM so each chunk is in one tensor
    const float* __restrict__ xsrc = (kbase < NDIM) ? t1 : t2;
    const int koff = (kbase < NDIM) ? kbase : (kbase - NDIM);
    const float* __restrict__ xb0 = xsrc + (size_t)(tok0 + n) * NDIM + koff + fq * 8;
    const float* __restrict__ xb1 = xsrc + (size_t)(tok0 + 16 + n) * NDIM + koff + fq * 8;
    // W: fragment-major; k-octet index = kbase/8 + s*4 + fq, expert row 16j+n
    const _Float16* __restrict__ whb = WhT + ((size_t)(kbase >> 3) + fq) * (NEXP * 8) + n * 8;
    const _Float16* __restrict__ wlb = WlT + ((size_t)(kbase >> 3) + fq) * (NEXP * 8) + n * 8;

    floatx4 acc[2][4];
    #pragma unroll
    for (int tt = 0; tt < 2; ++tt)
        #pragma unroll
        for (int j = 0; j < 4; ++j) { acc[tt][j][0]=0.f; acc[tt][j][1]=0.f; acc[tt][j][2]=0.f; acc[tt][j][3]=0.f; }
    float ss0a = 0.f, ss0b = 0.f, ss1a = 0.f, ss1b = 0.f;

    #pragma unroll
    for (int s = 0; s < NSTEP; ++s) {
        const float4 x00 = *reinterpret_cast<const float4*>(xb0 + s * 32);
        const float4 x01 = *reinterpret_cast<const float4*>(xb0 + s * 32 + 4);
        const float4 x10 = *reinterpret_cast<const float4*>(xb1 + s * 32);
        const float4 x11 = *reinterpret_cast<const float4*>(xb1 + s * 32 + 4);
        half8 bh[4], bl[4];
        #pragma unroll
        for (int j = 0; j < 4; ++j) {
            bh[j] = *reinterpret_cast<const half8*>(whb + (size_t)s * 4 * (NEXP * 8) + j * 128);
            bl[j] = *reinterpret_cast<const half8*>(wlb + (size_t)s * 4 * (NEXP * 8) + j * 128);
        }
        ss0a = fmaf(x00.x, x00.x, fmaf(x00.y, x00.y, fmaf(x00.z, x00.z, fmaf(x00.w, x00.w, ss0a))));
        ss0b = fmaf(x01.x, x01.x, fmaf(x01.y, x01.y, fmaf(x01.z, x01.z, fmaf(x01.w, x01.w, ss0b))));
        ss1a = fmaf(x10.x, x10.x, fmaf(x10.y, x10.y, fmaf(x10.z, x10.z, fmaf(x10.w, x10.w, ss1a))));
        ss1b = fmaf(x11.x, x11.x, fmaf(x11.y, x11.y, fmaf(x11.z, x11.z, fmaf(x11.w, x11.w, ss1b))));
        const h2pair q0 = split2(x00.x * XSCALE), q1 = split2(x00.y * XSCALE);
        const h2pair q2 = split2(x00.z * XSCALE), q3 = split2(x00.w * XSCALE);
        const h2pair q4 = split2(x01.x * XSCALE), q5 = split2(x01.y * XSCALE);
        const h2pair q6 = split2(x01.z * XSCALE), q7 = split2(x01.w * XSCALE);
        const h2pair r0 = split2(x10.x * XSCALE), r1 = split2(x10.y * XSCALE);
        const h2pair r2 = split2(x10.z * XSCALE), r3 = split2(x10.w * XSCALE);
        const h2pair r4 = split2(x11.x * XSCALE), r5 = split2(x11.y * XSCALE);
        const h2pair r6 = split2(x11.z * XSCALE), r7 = split2(x11.w * XSCALE);
        half8 ah0, al0, ah1, al1;
        ah0[0]=q0.h; ah0[1]=q1.h; ah0[2]=q2.h; ah0[3]=q3.h; ah0[4]=q4.h; ah0[5]=q5.h; ah0[6]=q6.h; ah0[7]=q7.h;
        al0[0]=q0.l; al0[1]=q1.l; al0[2]=q2.l; al0[3]=q3.l; al0[4]=q4.l; al0[5]=q5.l; al0[6]=q6.l; al0[7]=q7.l;
        ah1[0]=r0.h; ah1[1]=r1.h; ah1[2]=r2.h; ah1[3]=r3.h; ah1[4]=r4.h; ah1[5]=r5.h; ah1[6]=r6.h; ah1[7]=r7.h;
        al1[0]=r0.l; al1[1]=r1.l; al1[2]=r2.l; al1[3]=r3.l; al1[4]=r4.l; al1[5]=r5.l; al1[6]=r6.l; al1[7]=r7.l;
        // Each B fragment feeds both A-tiles: W vmem amortized 2x.
        #pragma unroll
        for (int j = 0; j < 4; ++j) {
            acc[0][j] = __builtin_amdgcn_mfma_f32_16x16x32_f16(ah0, bh[j], acc[0][j], 0, 0, 0);
            acc[1][j] = __builtin_amdgcn_mfma_f32_16x16x32_f16(ah1, bh[j], acc[1][j], 0, 0, 0);
        }
        #pragma unroll
        for (int j = 0; j < 4; ++j) {
            acc[0][j] = __builtin_amdgcn_mfma_f32_16x16x32_f16(al0, bh[j], acc[0][j], 0, 0, 0);
            acc[1][j] = __builtin_amdgcn_mfma_f32_16x16x32_f16(al1, bh[j], acc[1][j], 0, 0, 0);
        }
        #pragma unroll
        for (int j = 0; j < 4; ++j) {
            acc[0][j] = __builtin_amdgcn_mfma_f32_16x16x32_f16(ah0, bl[j], acc[0][j], 0, 0, 0);
            acc[1][j] = __builtin_amdgcn_mfma_f32_16x16x32_f16(ah1, bl[j], acc[1][j], 0, 0, 0);
        }
    }

    // ---- deposit partial dots (C/D layout: token = tt*16 + fq*4+i, expert 16j+n)
    #pragma unroll
    for (int tt = 0; tt < 2; ++tt)
        #pragma unroll
        for (int j = 0; j < 4; ++j)
            #pragma unroll
            for (int i = 0; i < 4; ++i)
                Sd[wv][(tt * 16 + fq * 4 + i) * RS + 16 * j + n] = acc[tt][j][i];

    // ---- token norm partials: combine the 4 fq-lanes of each token ----
    float ss0 = ss0a + ss0b, ss1 = ss1a + ss1b;
    ss0 += __shfl_xor(ss0, 16, 64);
    ss0 += __shfl_xor(ss0, 32, 64);
    ss1 += __shfl_xor(ss1, 16, 64);
    ss1 += __shfl_xor(ss1, 32, 64);
    if (lane < 16) { Cn[wv][lane] = ss0; Cn[wv][16 + lane] = ss1; }
    __syncthreads();

    // ---- reduce over the 8 intra-block waves; write partials (wave w: 4 tokens)
    #pragma unroll
    for (int tt = 0; tt < 4; ++tt) {
        const int t = wv * 4 + tt;
        float gsum = 0.f, csum = 0.f;
        #pragma unroll
        for (int w = 0; w < NWAVE; ++w) {
            gsum += Sd[w][t * RS + lane];
            csum += Cn[w][t];
        }
        dotp[((size_t)(tile * 2 + kb) * TPB_TOK + t) * NEXP + lane] = gsum;
        if (lane == 0) xnp[(size_t)(tile * 2 + kb) * TPB_TOK + t] = csum;
    }
}

// ---------------------------------------------------------------------------
// finalize: one wave per token — combine the 2 K-half partials, then
// logit = -sqrt(||x||^2 - 2 x.w + ||w||^2), top-2, softmax, scatter.
// grid = 512 blocks x 512 threads (8 waves = 8 tokens per block).
// ---------------------------------------------------------------------------
__global__ __launch_bounds__(512) void finalize(const float* __restrict__ dotp,
                                                const float* __restrict__ xnp,
                                                const float* __restrict__ nrm,
                                                float* __restrict__ out) {
    const int tid  = threadIdx.x;
    const int lane = tid & 63;
    const int wv   = tid >> 6;
    const int tok  = blockIdx.x * 8 + wv;
    const int tile = tok >> 5;            // /TPB_TOK
    const int t    = tok & 31;

    const float g = dotp[((size_t)(tile * 2 + 0) * TPB_TOK + t) * NEXP + lane]
                  + dotp[((size_t)(tile * 2 + 1) * TPB_TOK + t) * NEXP + lane];
    const float c = xnp[(size_t)(tile * 2 + 0) * TPB_TOK + t]
                  + xnp[(size_t)(tile * 2 + 1) * TPB_TOK + t];
    const float S = fmaf(-2.f * INVSCALE, g, c) + nrm[lane];
    const float logit = -sqrtf(S);

    float v1 = logit; int i1 = lane;
    #pragma unroll
    for (int off = 32; off > 0; off >>= 1) {
        float ov = __shfl_xor(v1, off, 64);
        int   oi = __shfl_xor(i1, off, 64);
        if (ov > v1 || (ov == v1 && oi < i1)) { v1 = ov; i1 = oi; }
    }
    float v2 = (lane == i1) ? -__builtin_inff() : logit;
    int   i2 = lane;
    #pragma unroll
    for (int off = 32; off > 0; off >>= 1) {
        float ov = __shfl_xor(v2, off, 64);
        int   oi = __shfl_xor(i2, off, 64);
        if (ov > v2 || (ov == v2 && oi < i2)) { v2 = ov; i2 = oi; }
    }
    const float e2  = expf(v2 - v1);
    const float inv = 1.f / (1.f + e2);
    const float o = (lane == i1) ? inv : ((lane == i2) ? e2 * inv : 0.f);
    out[(size_t)tok * NEXP + lane] = o;
}

// ---------------------------------------------------------------------------
extern "C" void kernel_launch(void* const* d_in, const int* in_sizes, int n_in,
                              void* d_out, int out_size, void* d_ws, size_t ws_size,
                              hipStream_t stream) {
    const float* t1 = (const float*)d_in[0];
    const float* t2 = (const float*)d_in[1];
    const float* W  = (const float*)d_in[2];
    float* out = (float*)d_out;

    char* ws = (char*)d_ws;
    float*    nrm  = (float*)ws;                        // 64 floats
    _Float16* WhT  = (_Float16*)(nrm + NEXP);           // 131072 halves (256 KB)
    _Float16* WlT  = WhT + (size_t)NEXP * KTOT;         // 256 KB
    float*    dotp = (float*)(WlT + (size_t)NEXP * KTOT);   // 256*32*64 floats (2 MB)
    float*    xnp  = dotp + (size_t)NTILE * 2 * TPB_TOK * NEXP; // 8192 floats

    prep_w<<<NEXP, 256, 0, stream>>>(W, WhT, WlT, nrm);
    gate_main<<<NTILE * 2, 512, 0, stream>>>(t1, t2, WhT, WlT, dotp, xnp);
    finalize<<<NTOK / 8, 512, 0, stream>>>(dotp, xnp, nrm, out);
}